// Round 6
// baseline (777.661 us; speedup 1.0000x reference)
//
#include <hip/hip_runtime.h>

// LIF layer: Wx = x @ W^T (x:[B,T,I] f32, W:[H,I] f32), then sequential scan
// over T:  u = al*(u - s) + (1-al)*wx ;  s = (u - 1 > 0) ? 1 : 0.
// fp32 end-to-end; accumulation order (sequential-k fma per (m,n)) bitwise-
// identical to R0..R6 (absmax == 0.0).
//
// R7: GEMM gets the T14 async-STAGE split with a SINGLE LDS buffer:
//   issue tile k+1 global loads (16 named VGPRs) -> compute tile k (2048 cy)
//   -> barrier -> ds_write regs -> barrier.
// The ~900cy HBM staging latency was fully exposed per tile (loads -> vmcnt ->
// ds_write -> barrier -> compute, nothing to overlap in-block); 2048/2948=69%
// matches the 57% fma-issue / 75% VALUBusy seen in R3-R6. LDS is NOT the
// bottleneck (broadcast dedup: ~640 unique B/wave/kstep = 5cy vs 128cy fma).
// R2's failure was double-buffer+v2f codegen (184 VGPR), not the split.
// Scan: aux=2 (NT) on global_load_lds; nt spike stores kept.

#define ALPHA_LO_F ((float)0.8187307530779818)   // exp(-1/5)
#define ALPHA_HI_F ((float)0.9607894391523232)   // exp(-1/25)

typedef float v4f __attribute__((ext_vector_type(4)));

// ---------------------------------------------------------------------------
// Kernel 1: fp32 NT GEMM, 128x128 tile, BK=16, 256 threads, 8x8 acc/thread.
// LDS As[k][m], Bs[k][n]; staging scatter-writes 2-way aliased (free, m136).
// A reads: 4 unique 16B addrs broadcast x16 lanes = clean. B reads: 4+4 col
// split -> 16 contiguous 16B chunks, worst 2-way at the 128B wrap.
// ---------------------------------------------------------------------------
#define TM 128
#define TN 128
#define TK 16
__global__ __launch_bounds__(256) void gemm_nt_f32(
    const float* __restrict__ A,   // [M, K]
    const float* __restrict__ B,   // [N, K]
    float* __restrict__ C,         // [M, N]
    int M, int N, int K)
{
    __shared__ float As[TK][TM];
    __shared__ float Bs[TK][TN];

    const int tid = threadIdx.x;
    const int m0  = blockIdx.y * TM;
    const int n0  = blockIdx.x * TN;

    // staging map: row = tid>>1 (0..127), kq = (tid&1)*8; two float4 per tile
    const int lrow = tid >> 1;
    const int lkq  = (tid & 1) * 8;

    // compute map: 16x16 threads; rows tm*8..+7; cols {tn*4..+3} u {64+tn*4..+3}
    const int tm = tid >> 4;     // 0..15
    const int tn = tid & 15;     // 0..15

    float acc[8][8] = {};

    const float* Arow = A + (size_t)(m0 + lrow) * K + lkq;
    const float* Brow = B + (size_t)(n0 + lrow) * K + lkq;

    // ---- prologue: stage tile 0
    {
        float4 av0 = *(const float4*)(Arow);
        float4 av1 = *(const float4*)(Arow + 4);
        float4 bv0 = *(const float4*)(Brow);
        float4 bv1 = *(const float4*)(Brow + 4);
        As[lkq + 0][lrow] = av0.x;  As[lkq + 1][lrow] = av0.y;
        As[lkq + 2][lrow] = av0.z;  As[lkq + 3][lrow] = av0.w;
        As[lkq + 4][lrow] = av1.x;  As[lkq + 5][lrow] = av1.y;
        As[lkq + 6][lrow] = av1.z;  As[lkq + 7][lrow] = av1.w;
        Bs[lkq + 0][lrow] = bv0.x;  Bs[lkq + 1][lrow] = bv0.y;
        Bs[lkq + 2][lrow] = bv0.z;  Bs[lkq + 3][lrow] = bv0.w;
        Bs[lkq + 4][lrow] = bv1.x;  Bs[lkq + 5][lrow] = bv1.y;
        Bs[lkq + 6][lrow] = bv1.z;  Bs[lkq + 7][lrow] = bv1.w;
    }
    __syncthreads();

    const int NT = K / TK;
    for (int kt = 0; kt < NT; ++kt) {
        // T14 issue-early: next tile's loads in flight across the compute phase
        float4 nav0, nav1, nbv0, nbv1;
        if (kt + 1 < NT) {
            const float* An = Arow + (size_t)(kt + 1) * TK;
            const float* Bn = Brow + (size_t)(kt + 1) * TK;
            nav0 = *(const float4*)(An);
            nav1 = *(const float4*)(An + 4);
            nbv0 = *(const float4*)(Bn);
            nbv1 = *(const float4*)(Bn + 4);
        }

        #pragma unroll
        for (int k = 0; k < TK; ++k) {
            const float* Ak  = &As[k][tm * 8];
            const float* Bk0 = &Bs[k][tn * 4];        // conflict-free b128
            const float* Bk1 = &Bs[k][64 + tn * 4];   // conflict-free b128
            float4 a0 = *(const float4*)(Ak);
            float4 a1 = *(const float4*)(Ak + 4);
            float4 b0 = *(const float4*)(Bk0);
            float4 b1 = *(const float4*)(Bk1);
            float a[8]  = {a0.x, a0.y, a0.z, a0.w, a1.x, a1.y, a1.z, a1.w};
            float bv[8] = {b0.x, b0.y, b0.z, b0.w, b1.x, b1.y, b1.z, b1.w};
            #pragma unroll
            for (int i = 0; i < 8; ++i) {
                #pragma unroll
                for (int j = 0; j < 8; ++j)
                    acc[i][j] = __builtin_fmaf(a[i], bv[j], acc[i][j]);
            }
        }
        __syncthreads();               // all waves done READING the LDS tile

        if (kt + 1 < NT) {
            // T14 write-late: vmcnt wait lands here, after 2048cy of compute
            As[lkq + 0][lrow] = nav0.x;  As[lkq + 1][lrow] = nav0.y;
            As[lkq + 2][lrow] = nav0.z;  As[lkq + 3][lrow] = nav0.w;
            As[lkq + 4][lrow] = nav1.x;  As[lkq + 5][lrow] = nav1.y;
            As[lkq + 6][lrow] = nav1.z;  As[lkq + 7][lrow] = nav1.w;
            Bs[lkq + 0][lrow] = nbv0.x;  Bs[lkq + 1][lrow] = nbv0.y;
            Bs[lkq + 2][lrow] = nbv0.z;  Bs[lkq + 3][lrow] = nbv0.w;
            Bs[lkq + 4][lrow] = nbv1.x;  Bs[lkq + 5][lrow] = nbv1.y;
            Bs[lkq + 6][lrow] = nbv1.z;  Bs[lkq + 7][lrow] = nbv1.w;
            __syncthreads();           // LDS ready for next tile
        }
    }

    #pragma unroll
    for (int i = 0; i < 8; ++i) {
        float* Crow = C + (size_t)(m0 + tm * 8 + i) * N + n0;
        v4f v0, v1;
        v0.x = acc[i][0]; v0.y = acc[i][1]; v0.z = acc[i][2]; v0.w = acc[i][3];
        v1.x = acc[i][4]; v1.y = acc[i][5]; v1.z = acc[i][6]; v1.w = acc[i][7];
        __builtin_nontemporal_store(v0, (v4f*)(Crow + tn * 4));
        __builtin_nontemporal_store(v1, (v4f*)(Crow + 64 + tn * 4));
    }
}

// ---------------------------------------------------------------------------
// Kernel 2: LIF scan, producer/consumer (structure unchanged from R2-R6;
// loads now NT cache policy, spike writes non-temporal).
// Block = 320 threads (5 waves) per (b, 64-h slab). Wave 0 computes the
// recurrence out of LDS; waves 1..4 stream Wx chunks (C_T=64 t-steps x 64 h
// = 16 KB) into a 4-deep LDS ring with global_load_lds dwordx4.
// Counted vmcnt(12) keeps 3 chunks (48 KB/block) in flight across barriers.
// ---------------------------------------------------------------------------
#define C_T  64
#define NBUF 4

__global__ __launch_bounds__(320) void lif_scan(
    float* __restrict__ buf,            // [B, T, H]: in = Wx, out = spikes
    const float* __restrict__ alpha,    // [H]
    const float* __restrict__ u0,       // [B, H]
    const float* __restrict__ s0,       // [B, H]
    int B, int T, int H)
{
    __shared__ float S[NBUF][C_T][64];  // 64 KB ring

    const int tid  = threadIdx.x;
    const int wid  = tid >> 6;
    const int lane = tid & 63;
    const int b    = blockIdx.y;
    const int h0   = blockIdx.x * 64;
    const int nch  = T / C_T;           // 16 for T=1024

    float* base = buf + (size_t)b * T * H + h0;

    if (wid == 0) {
        // ---- compute wave: lane = h within slab
        const int h = h0 + lane;
        float al = alpha[h];
        al = fminf(fmaxf(al, ALPHA_LO_F), ALPHA_HI_F);
        const float oma = 1.0f - al;
        float u = u0[(size_t)b * H + h];
        float s = s0[(size_t)b * H + h];

        for (int j = 0; j < nch; ++j) {
            asm volatile("s_barrier" ::: "memory");           // A: chunk j ready
            const float* Sj = &S[j & (NBUF - 1)][0][0] + lane;
            float* orow = base + (size_t)j * C_T * H + lane;
            for (int tb = 0; tb < C_T; tb += 16) {
                float w[16];
                #pragma unroll
                for (int tt = 0; tt < 16; ++tt)
                    w[tt] = Sj[(tb + tt) * 64];
                #pragma unroll
                for (int tt = 0; tt < 16; ++tt) {
                    u = al * (u - s) + oma * w[tt];           // same fp32 expr as R0/R1
                    s = (u - 1.0f > 0.0f) ? 1.0f : 0.0f;
                    w[tt] = s;
                }
                #pragma unroll
                for (int tt = 0; tt < 16; ++tt)
                    __builtin_nontemporal_store(w[tt], &orow[(size_t)(tb + tt) * H]);
            }
            // all LDS reads hard-complete before loaders may overwrite the buf
            asm volatile("s_waitcnt lgkmcnt(0)" ::: "memory");
            asm volatile("s_barrier" ::: "memory");           // B: buffer free
        }
    } else {
        // ---- loader waves: wave lw issues instrs i = lw + 4q, q=0..3 per chunk.
        // instr i covers LDS bytes [i*1024, i*1024+1024): t = i*4 + (lane>>4),
        // h = (lane&15)*4; dest = uniform base + lane*16 (linear, matches).
        // aux=2 -> NT cache policy: don't allocate the streamed read in L2.
        const int lw = wid - 1;          // 0..3

        #define ISSUE_CHUNK(c)                                                  \
            {                                                                   \
                const int cc = (c);                                             \
                char* sb = (char*)&S[cc & (NBUF - 1)][0][0];                    \
                _Pragma("unroll")                                               \
                for (int q = 0; q < 4; ++q) {                                   \
                    const int i = lw + 4 * q;                                   \
                    const int t = cc * C_T + i * 4 + (lane >> 4);               \
                    const float* g = base + (size_t)t * H + (lane & 15) * 4;    \
                    __builtin_amdgcn_global_load_lds(                           \
                        (const __attribute__((address_space(1))) unsigned int*)g, \
                        (__attribute__((address_space(3))) unsigned int*)(sb + i * 1024), \
                        16, 0, 2);                                              \
                }                                                               \
            }

        // prologue: chunks 0..NBUF-2 (3 chunks, 48 KB in flight)
        for (int c = 0; c < NBUF - 1; ++c) ISSUE_CHUNK(c)

        for (int j = 0; j < nch; ++j) {
            const int c = j + NBUF - 1;
            if (c < nch) ISSUE_CHUNK(c)
            // wait: chunk j complete; allow chunks j+1..j+3 (4 instr each) in flight
            if (j < nch - 3)       asm volatile("s_waitcnt vmcnt(12)" ::: "memory");
            else if (j == nch - 3) asm volatile("s_waitcnt vmcnt(8)"  ::: "memory");
            else if (j == nch - 2) asm volatile("s_waitcnt vmcnt(4)"  ::: "memory");
            else                   asm volatile("s_waitcnt vmcnt(0)"  ::: "memory");
            asm volatile("s_barrier" ::: "memory");           // A: publish chunk j
            asm volatile("s_barrier" ::: "memory");           // B: compute done
        }
        #undef ISSUE_CHUNK
    }
}

extern "C" void kernel_launch(void* const* d_in, const int* in_sizes, int n_in,
                              void* d_out, int out_size, void* d_ws, size_t ws_size,
                              hipStream_t stream) {
    const float* x     = (const float*)d_in[0];   // [B, T, I]
    const float* W     = (const float*)d_in[1];   // [H, I]
    const float* alpha = (const float*)d_in[2];   // [H]
    const float* u0    = (const float*)d_in[3];   // [B, H]
    const float* s0    = (const float*)d_in[4];   // [B, H]
    float* out = (float*)d_out;                   // [B, T, H]

    const int H = in_sizes[2];
    const int I = in_sizes[1] / H;
    const int B = in_sizes[3] / H;
    const int T = in_sizes[0] / (B * I);
    const int M = B * T;

    // 1) Wx -> d_out (exactly [B,T,H] f32; reused in-place by the scan)
    dim3 grid1(H / TN, M / TM);
    gemm_nt_f32<<<grid1, 256, 0, stream>>>(x, W, out, M, H, I);

    // 2) scan over T, in-place, producer/consumer
    dim3 grid2(H / 64, B);
    lif_scan<<<grid2, 320, 0, stream>>>(out, alpha, u0, s0, B, T, H);
}

// Round 7
// 740.872 us; speedup vs baseline: 1.0497x; 1.0497x over previous
//
#include <hip/hip_runtime.h>

// LIF layer, FUSED: per block (b, 64-h slab), for each 128-row t-tile:
//   Wx-tile = x[b, t-tile, :] @ W[slab, :]^T   (R6's verified 2-barrier GEMM)
//   -> LDS -> wave0 scans 128 t-steps (u = al*(u-s)+(1-al)*wx; s = u-1>0)
//   -> nt-store spikes. Wx NEVER touches HBM (saves 268 MB + the ~219us
//   scan kernel, which was pinned at 1.2 TB/s across two structures).
// Accumulation order per (t,h) = sequential-k fma, identical to R0..R7;
// scan expression identical -> absmax 0.0 end-to-end.
//
// R7 post-mortem: holding prefetch regs across the unrolled compute makes
// hipcc pipeline the whole body (VGPR 52->184, occupancy 12%) -- same as R2.
// The plain 2-barrier loop + resident-wave TLP is the stable GEMM structure;
// this round changes the DATAFLOW, not the loop.

#define ALPHA_LO_F ((float)0.8187307530779818)   // exp(-1/5)
#define ALPHA_HI_F ((float)0.9607894391523232)   // exp(-1/25)

typedef float v4f __attribute__((ext_vector_type(4)));

#define FTM 128   // t-tile rows
#define FTN 64    // h-slab width
#define FTK 16    // k step

// LDS: As 8KB + Bs 4KB + Wxs 32KB = 44KB -> 2 blocks/CU (grid-limited anyway).
// Bank audit: As writes 2-way (free); Bs writes 4-way on 4xb32 (tiny);
// A reads 4 addrs 32B apart broadcast x16 = clean; B reads 16x16B over 256B
// = 2-way wrap (free); Wxs writes 4-way b128 (8/thread/tile, accepted);
// Wxs scan reads stride-1 across lanes = 2-way (free).
__global__ __launch_bounds__(256) void lif_fused(
    const float* __restrict__ x,     // [B, T, I]
    const float* __restrict__ W,     // [H, I]
    const float* __restrict__ alpha, // [H]
    const float* __restrict__ u0,    // [B, H]
    const float* __restrict__ s0,    // [B, H]
    float* __restrict__ out,         // [B, T, H]
    int Bn, int T, int I, int H)
{
    __shared__ float As[FTK][FTM];
    __shared__ float Bs[FTK][FTN];
    __shared__ float Wxs[FTM][FTN];

    const int tid = threadIdx.x;
    const int h0  = blockIdx.x * FTN;
    const int b   = blockIdx.y;

    // A staging: lrow 0..127, lkq in {0,8}: two float4 per k-tile
    const int lrow = tid >> 1;
    const int lkq  = (tid & 1) * 8;
    // B staging: brow 0..63, bkq in {0,4,8,12}: one float4 per k-tile
    const int brow = tid >> 2;
    const int bkq  = (tid & 3) * 4;

    // compute map: rows tm*8..+7 (t), cols tn*4..+3 (h)
    const int tm = tid >> 4;     // 0..15
    const int tn = tid & 15;     // 0..15

    // persistent scan state: thread tid<64 owns h = h0+tid
    float u = 0.0f, s = 0.0f, al = 0.0f, oma = 0.0f;
    if (tid < FTN) {
        float a_ = alpha[h0 + tid];
        a_ = fminf(fmaxf(a_, ALPHA_LO_F), ALPHA_HI_F);
        al = a_;  oma = 1.0f - a_;
        u = u0[(size_t)b * H + h0 + tid];
        s = s0[(size_t)b * H + h0 + tid];
    }

    const float* Wrow = W + (size_t)(h0 + brow) * I + bkq;

    for (int t0 = 0; t0 < T; t0 += FTM) {
        const float* Arow = x + ((size_t)b * T + t0 + lrow) * I + lkq;
        float acc[8][4] = {};

        for (int k0 = 0; k0 < I; k0 += FTK) {
            float4 av0 = *(const float4*)(Arow + k0);
            float4 av1 = *(const float4*)(Arow + k0 + 4);
            float4 bv  = *(const float4*)(Wrow + k0);
            As[lkq + 0][lrow] = av0.x;  As[lkq + 1][lrow] = av0.y;
            As[lkq + 2][lrow] = av0.z;  As[lkq + 3][lrow] = av0.w;
            As[lkq + 4][lrow] = av1.x;  As[lkq + 5][lrow] = av1.y;
            As[lkq + 6][lrow] = av1.z;  As[lkq + 7][lrow] = av1.w;
            Bs[bkq + 0][brow] = bv.x;   Bs[bkq + 1][brow] = bv.y;
            Bs[bkq + 2][brow] = bv.z;   Bs[bkq + 3][brow] = bv.w;
            __syncthreads();

            #pragma unroll
            for (int k = 0; k < FTK; ++k) {
                const float* Ak = &As[k][tm * 8];
                const float* Bk = &Bs[k][tn * 4];
                float4 a0 = *(const float4*)(Ak);
                float4 a1 = *(const float4*)(Ak + 4);
                float4 b0 = *(const float4*)(Bk);
                float a[8]  = {a0.x, a0.y, a0.z, a0.w, a1.x, a1.y, a1.z, a1.w};
                float bb[4] = {b0.x, b0.y, b0.z, b0.w};
                #pragma unroll
                for (int i = 0; i < 8; ++i) {
                    #pragma unroll
                    for (int j = 0; j < 4; ++j)
                        acc[i][j] = __builtin_fmaf(a[i], bb[j], acc[i][j]);
                }
            }
            __syncthreads();
        }

        // acc -> Wxs (fp32-exact; same bits as the old HBM round-trip)
        #pragma unroll
        for (int i = 0; i < 8; ++i) {
            v4f v;
            v.x = acc[i][0]; v.y = acc[i][1]; v.z = acc[i][2]; v.w = acc[i][3];
            *(v4f*)(&Wxs[tm * 8 + i][tn * 4]) = v;
        }
        __syncthreads();

        // scan this t-tile (wave 0; h = tid), batched-16 LDS reads to keep
        // ds_read latency off the dependence chain
        if (tid < FTN) {
            float* orow = out + ((size_t)b * T + t0) * H + h0 + tid;
            for (int tb = 0; tb < FTM; tb += 16) {
                float w[16];
                #pragma unroll
                for (int q = 0; q < 16; ++q)
                    w[q] = Wxs[tb + q][tid];
                #pragma unroll
                for (int q = 0; q < 16; ++q) {
                    u = al * (u - s) + oma * w[q];   // same fp32 expr as R0..R7
                    s = (u - 1.0f > 0.0f) ? 1.0f : 0.0f;
                    w[q] = s;
                }
                #pragma unroll
                for (int q = 0; q < 16; ++q)
                    __builtin_nontemporal_store(w[q], orow + (size_t)(tb + q) * H);
            }
        }
        __syncthreads();   // Wxs free for the next t-tile
    }
}

extern "C" void kernel_launch(void* const* d_in, const int* in_sizes, int n_in,
                              void* d_out, int out_size, void* d_ws, size_t ws_size,
                              hipStream_t stream) {
    const float* x     = (const float*)d_in[0];   // [B, T, I]
    const float* W     = (const float*)d_in[1];   // [H, I]
    const float* alpha = (const float*)d_in[2];   // [H]
    const float* u0    = (const float*)d_in[3];   // [B, H]
    const float* s0    = (const float*)d_in[4];   // [B, H]
    float* out = (float*)d_out;                   // [B, T, H]

    const int H = in_sizes[2];
    const int I = in_sizes[1] / H;
    const int B = in_sizes[3] / H;
    const int T = in_sizes[0] / (B * I);

    dim3 grid(H / FTN, B);
    lif_fused<<<grid, 256, 0, stream>>>(x, W, alpha, u0, s0, out, B, T, I, H);
}

// Round 8
// 627.944 us; speedup vs baseline: 1.2384x; 1.1798x over previous
//
#include <hip/hip_runtime.h>

// LIF layer: Wx = x @ W^T, then sequential scan over T.
// fp32 end-to-end; per-(t,h) sequential-k fma chain identical to R0..R7
// (absmax == 0.0). Scan expression identical.
//
// R8: scan input made CONTIGUOUS. GEMM writes Wx to d_ws in slab-blocked
// layout [B][H/64][T][64] (only the C-store address map changes); each scan
// block then reads a contiguous 256KB stream and writes spikes to out
// (separate region -- no in-place RMW). Producer/consumer ring otherwise
// byte-identical to R6, isolating access pattern as the single variable.
// Theory: scan pinned at 1.2 TB/s across two structures because 512 blocks
// stream 256B segments at 2KB stride in-place; 24MB in flight >> latency-BW
// product, so the limiter is DRAM service rate of the fragmented pattern.
// Fallback: if ws_size < out_size, R6 in-place path.

#define ALPHA_LO_F ((float)0.8187307530779818)   // exp(-1/5)
#define ALPHA_HI_F ((float)0.9607894391523232)   // exp(-1/25)

typedef float v4f __attribute__((ext_vector_type(4)));

// ---------------------------------------------------------------------------
// Kernel 1: fp32 NT GEMM, 128x128 tile, BK=16, 256 threads, 8x8 acc/thread.
// BLK=1: C-store remapped to [B][NS][T][64] blocked layout in ws (compute
// identical; 16B stores stay within one slab since tn*4+3 < 64).
// ---------------------------------------------------------------------------
#define TM 128
#define TN 128
#define TK 16
template <int BLK>
__global__ __launch_bounds__(256) void gemm_nt_f32(
    const float* __restrict__ A,   // [M, K]
    const float* __restrict__ B,   // [N, K]
    float* __restrict__ C,         // BLK=0: [M,N]; BLK=1: [B][N/64][T][64]
    int M, int N, int K, int T)
{
    __shared__ float As[TK][TM];
    __shared__ float Bs[TK][TN];

    const int tid = threadIdx.x;
    const int m0  = blockIdx.y * TM;
    const int n0  = blockIdx.x * TN;

    // staging map: row = tid>>1 (0..127), kq = (tid&1)*8; two float4 per tile
    const int lrow = tid >> 1;
    const int lkq  = (tid & 1) * 8;

    // compute map: 16x16 threads; rows tm*8..+7; cols {tn*4..+3} u {64+tn*4..+3}
    const int tm = tid >> 4;     // 0..15
    const int tn = tid & 15;     // 0..15

    float acc[8][8] = {};

    const float* Arow = A + (size_t)(m0 + lrow) * K + lkq;
    const float* Brow = B + (size_t)(n0 + lrow) * K + lkq;

    for (int k0 = 0; k0 < K; k0 += TK) {
        float4 av0 = *(const float4*)(Arow + k0);
        float4 av1 = *(const float4*)(Arow + k0 + 4);
        float4 bv0 = *(const float4*)(Brow + k0);
        float4 bv1 = *(const float4*)(Brow + k0 + 4);
        As[lkq + 0][lrow] = av0.x;  As[lkq + 1][lrow] = av0.y;
        As[lkq + 2][lrow] = av0.z;  As[lkq + 3][lrow] = av0.w;
        As[lkq + 4][lrow] = av1.x;  As[lkq + 5][lrow] = av1.y;
        As[lkq + 6][lrow] = av1.z;  As[lkq + 7][lrow] = av1.w;
        Bs[lkq + 0][lrow] = bv0.x;  Bs[lkq + 1][lrow] = bv0.y;
        Bs[lkq + 2][lrow] = bv0.z;  Bs[lkq + 3][lrow] = bv0.w;
        Bs[lkq + 4][lrow] = bv1.x;  Bs[lkq + 5][lrow] = bv1.y;
        Bs[lkq + 6][lrow] = bv1.z;  Bs[lkq + 7][lrow] = bv1.w;
        __syncthreads();

        #pragma unroll
        for (int k = 0; k < TK; ++k) {
            const float* Ak  = &As[k][tm * 8];
            const float* Bk0 = &Bs[k][tn * 4];        // conflict-free b128
            const float* Bk1 = &Bs[k][64 + tn * 4];   // conflict-free b128
            float4 a0 = *(const float4*)(Ak);
            float4 a1 = *(const float4*)(Ak + 4);
            float4 b0 = *(const float4*)(Bk0);
            float4 b1 = *(const float4*)(Bk1);
            float a[8]  = {a0.x, a0.y, a0.z, a0.w, a1.x, a1.y, a1.z, a1.w};
            float bv[8] = {b0.x, b0.y, b0.z, b0.w, b1.x, b1.y, b1.z, b1.w};
            #pragma unroll
            for (int i = 0; i < 8; ++i) {
                #pragma unroll
                for (int j = 0; j < 8; ++j)
                    acc[i][j] = __builtin_fmaf(a[i], bv[j], acc[i][j]);
            }
        }
        __syncthreads();
    }

    const int NS = N >> 6;   // slabs of 64 cols
    #pragma unroll
    for (int i = 0; i < 8; ++i) {
        const int row = m0 + tm * 8 + i;
        v4f v0, v1;
        v0.x = acc[i][0]; v0.y = acc[i][1]; v0.z = acc[i][2]; v0.w = acc[i][3];
        v1.x = acc[i][4]; v1.y = acc[i][5]; v1.z = acc[i][6]; v1.w = acc[i][7];
        if constexpr (BLK) {
            const int b = row / T, t = row - b * T;
            const int c0 = n0 + tn * 4, c1 = n0 + 64 + tn * 4;
            float* p0 = C + (((size_t)b * NS + (c0 >> 6)) * T + t) * 64 + (c0 & 63);
            float* p1 = C + (((size_t)b * NS + (c1 >> 6)) * T + t) * 64 + (c1 & 63);
            __builtin_nontemporal_store(v0, (v4f*)p0);
            __builtin_nontemporal_store(v1, (v4f*)p1);
        } else {
            float* Crow = C + (size_t)row * N + n0;
            __builtin_nontemporal_store(v0, (v4f*)(Crow + tn * 4));
            __builtin_nontemporal_store(v1, (v4f*)(Crow + 64 + tn * 4));
        }
    }
}

// ---------------------------------------------------------------------------
// Kernel 2a: LIF scan, blocked/contiguous source (ws), spikes to out.
// Block (s, b) reads ws slab [b*NS+s] = T*64 floats CONTIGUOUS via the same
// producer/consumer ring as R6 (4 loader waves, NBUF=4 x 16KB, counted vmcnt).
// ---------------------------------------------------------------------------
#define C_T  64
#define NBUF 4

__global__ __launch_bounds__(320) void lif_scan_blk(
    const float* __restrict__ ws,       // [B][NS][T][64]
    float* __restrict__ out,            // [B, T, H]
    const float* __restrict__ alpha,    // [H]
    const float* __restrict__ u0,       // [B, H]
    const float* __restrict__ s0,       // [B, H]
    int B, int T, int H)
{
    __shared__ float S[NBUF][C_T][64];  // 64 KB ring

    const int tid  = threadIdx.x;
    const int wid  = tid >> 6;
    const int lane = tid & 63;
    const int b    = blockIdx.y;
    const int sidx = blockIdx.x;        // slab within b
    const int h0   = sidx * 64;
    const int NS   = H >> 6;
    const int nch  = T / C_T;           // 16 for T=1024

    const float* src = ws + ((size_t)b * NS + sidx) * T * 64;   // contiguous

    if (wid == 0) {
        // ---- compute wave: lane = h within slab
        const int h = h0 + lane;
        float al = alpha[h];
        al = fminf(fmaxf(al, ALPHA_LO_F), ALPHA_HI_F);
        const float oma = 1.0f - al;
        float u = u0[(size_t)b * H + h];
        float s = s0[(size_t)b * H + h];

        for (int j = 0; j < nch; ++j) {
            asm volatile("s_barrier" ::: "memory");           // A: chunk j ready
            const float* Sj = &S[j & (NBUF - 1)][0][0] + lane;
            float* orow = out + ((size_t)b * T + j * C_T) * H + h;
            for (int tb = 0; tb < C_T; tb += 16) {
                float w[16];
                #pragma unroll
                for (int tt = 0; tt < 16; ++tt)
                    w[tt] = Sj[(tb + tt) * 64];
                #pragma unroll
                for (int tt = 0; tt < 16; ++tt) {
                    u = al * (u - s) + oma * w[tt];           // same fp32 expr
                    s = (u - 1.0f > 0.0f) ? 1.0f : 0.0f;
                    w[tt] = s;
                }
                #pragma unroll
                for (int tt = 0; tt < 16; ++tt)
                    __builtin_nontemporal_store(w[tt], orow + (size_t)(tb + tt) * H);
            }
            asm volatile("s_waitcnt lgkmcnt(0)" ::: "memory");
            asm volatile("s_barrier" ::: "memory");           // B: buffer free
        }
    } else {
        // ---- loader waves: contiguous stream; instr i covers chunk bytes
        // [i*1024, i*1024+1024); src and LDS dest both linear.
        const int lw = wid - 1;          // 0..3

        #define ISSUE_CHUNK(c)                                                  \
            {                                                                   \
                const int cc = (c);                                             \
                char* sb = (char*)&S[cc & (NBUF - 1)][0][0];                    \
                const float* gc = src + (size_t)cc * C_T * 64;                  \
                _Pragma("unroll")                                               \
                for (int q = 0; q < 4; ++q) {                                   \
                    const int i = lw + 4 * q;                                   \
                    const float* g = gc + i * 256 + lane * 4;                   \
                    __builtin_amdgcn_global_load_lds(                           \
                        (const __attribute__((address_space(1))) unsigned int*)g, \
                        (__attribute__((address_space(3))) unsigned int*)(sb + i * 1024), \
                        16, 0, 0);                                              \
                }                                                               \
            }

        for (int c = 0; c < NBUF - 1; ++c) ISSUE_CHUNK(c)

        for (int j = 0; j < nch; ++j) {
            const int c = j + NBUF - 1;
            if (c < nch) ISSUE_CHUNK(c)
            if (j < nch - 3)       asm volatile("s_waitcnt vmcnt(12)" ::: "memory");
            else if (j == nch - 3) asm volatile("s_waitcnt vmcnt(8)"  ::: "memory");
            else if (j == nch - 2) asm volatile("s_waitcnt vmcnt(4)"  ::: "memory");
            else                   asm volatile("s_waitcnt vmcnt(0)"  ::: "memory");
            asm volatile("s_barrier" ::: "memory");           // A: publish chunk j
            asm volatile("s_barrier" ::: "memory");           // B: compute done
        }
        #undef ISSUE_CHUNK
    }
}

// ---------------------------------------------------------------------------
// Kernel 2b: fallback in-place scan (R6 verified), used if ws too small.
// ---------------------------------------------------------------------------
__global__ __launch_bounds__(320) void lif_scan_ip(
    float* __restrict__ buf,            // [B, T, H]: in = Wx, out = spikes
    const float* __restrict__ alpha,
    const float* __restrict__ u0,
    const float* __restrict__ s0,
    int B, int T, int H)
{
    __shared__ float S[NBUF][C_T][64];

    const int tid  = threadIdx.x;
    const int wid  = tid >> 6;
    const int lane = tid & 63;
    const int b    = blockIdx.y;
    const int h0   = blockIdx.x * 64;
    const int nch  = T / C_T;

    float* base = buf + (size_t)b * T * H + h0;

    if (wid == 0) {
        const int h = h0 + lane;
        float al = alpha[h];
        al = fminf(fmaxf(al, ALPHA_LO_F), ALPHA_HI_F);
        const float oma = 1.0f - al;
        float u = u0[(size_t)b * H + h];
        float s = s0[(size_t)b * H + h];

        for (int j = 0; j < nch; ++j) {
            asm volatile("s_barrier" ::: "memory");
            const float* Sj = &S[j & (NBUF - 1)][0][0] + lane;
            float* orow = base + (size_t)j * C_T * H + lane;
            for (int tb = 0; tb < C_T; tb += 16) {
                float w[16];
                #pragma unroll
                for (int tt = 0; tt < 16; ++tt)
                    w[tt] = Sj[(tb + tt) * 64];
                #pragma unroll
                for (int tt = 0; tt < 16; ++tt) {
                    u = al * (u - s) + oma * w[tt];
                    s = (u - 1.0f > 0.0f) ? 1.0f : 0.0f;
                    w[tt] = s;
                }
                #pragma unroll
                for (int tt = 0; tt < 16; ++tt)
                    __builtin_nontemporal_store(w[tt], &orow[(size_t)(tb + tt) * H]);
            }
            asm volatile("s_waitcnt lgkmcnt(0)" ::: "memory");
            asm volatile("s_barrier" ::: "memory");
        }
    } else {
        const int lw = wid - 1;

        #define ISSUE_CHUNK(c)                                                  \
            {                                                                   \
                const int cc = (c);                                             \
                char* sb = (char*)&S[cc & (NBUF - 1)][0][0];                    \
                _Pragma("unroll")                                               \
                for (int q = 0; q < 4; ++q) {                                   \
                    const int i = lw + 4 * q;                                   \
                    const int t = cc * C_T + i * 4 + (lane >> 4);               \
                    const float* g = base + (size_t)t * H + (lane & 15) * 4;    \
                    __builtin_amdgcn_global_load_lds(                           \
                        (const __attribute__((address_space(1))) unsigned int*)g, \
                        (__attribute__((address_space(3))) unsigned int*)(sb + i * 1024), \
                        16, 0, 0);                                              \
                }                                                               \
            }

        for (int c = 0; c < NBUF - 1; ++c) ISSUE_CHUNK(c)

        for (int j = 0; j < nch; ++j) {
            const int c = j + NBUF - 1;
            if (c < nch) ISSUE_CHUNK(c)
            if (j < nch - 3)       asm volatile("s_waitcnt vmcnt(12)" ::: "memory");
            else if (j == nch - 3) asm volatile("s_waitcnt vmcnt(8)"  ::: "memory");
            else if (j == nch - 2) asm volatile("s_waitcnt vmcnt(4)"  ::: "memory");
            else                   asm volatile("s_waitcnt vmcnt(0)"  ::: "memory");
            asm volatile("s_barrier" ::: "memory");
            asm volatile("s_barrier" ::: "memory");
        }
        #undef ISSUE_CHUNK
    }
}

extern "C" void kernel_launch(void* const* d_in, const int* in_sizes, int n_in,
                              void* d_out, int out_size, void* d_ws, size_t ws_size,
                              hipStream_t stream) {
    const float* x     = (const float*)d_in[0];   // [B, T, I]
    const float* W     = (const float*)d_in[1];   // [H, I]
    const float* alpha = (const float*)d_in[2];   // [H]
    const float* u0    = (const float*)d_in[3];   // [B, H]
    const float* s0    = (const float*)d_in[4];   // [B, H]
    float* out = (float*)d_out;                   // [B, T, H]

    const int H = in_sizes[2];
    const int I = in_sizes[1] / H;
    const int B = in_sizes[3] / H;
    const int T = in_sizes[0] / (B * I);
    const int M = B * T;

    const size_t need = (size_t)M * H * sizeof(float);
    const bool blocked = (ws_size >= need) && ((H & 63) == 0) && (d_ws != nullptr);

    dim3 grid1(H / TN, M / TM);
    dim3 grid2(H / 64, B);

    if (blocked) {
        float* ws = (float*)d_ws;
        gemm_nt_f32<1><<<grid1, 256, 0, stream>>>(x, W, ws, M, H, I, T);
        lif_scan_blk<<<grid2, 320, 0, stream>>>(ws, out, alpha, u0, s0, B, T, H);
    } else {
        gemm_nt_f32<0><<<grid1, 256, 0, stream>>>(x, W, out, M, H, I, T);
        lif_scan_ip<<<grid2, 320, 0, stream>>>(out, alpha, u0, s0, B, T, H);
    }
}